// Round 5
// baseline (569.990 us; speedup 1.0000x reference)
//
#include <hip/hip_runtime.h>
#include <math.h>

// Problem constants (from the reference)
#define BB 8
#define TT 512
#define SS 512
#define HH 768
#define VOCAB 32110
#define NROWS (BB * TT)              // 4096
#define NCHUNK 4016                  // floats per vocab chunk
#define NCH 8                        // 7*4016 + 3998 = 32110
#define LASTN (VOCAB - 7 * NCHUNK)   // 3998
#define LDSPAD (NCHUNK + 4)          // 4020 floats = 16080 B per buffer
#define ROWS_PER_BLK 4
#define NBLK (NROWS / ROWS_PER_BLK)  // 1024 = 256 CUs * 4 blocks

typedef float v4f __attribute__((ext_vector_type(4)));  // native vec4 for nt-store

// ---------------------------------------------------------------------------
// Kernel 1: p_gen = sigmoid(concat(dec,seq) @ w + b)   -> out[0 .. B*T)
// ---------------------------------------------------------------------------
__global__ __launch_bounds__(256) void pgen_kernel(
    const float* __restrict__ dec,   // [B*T, H]
    const float* __restrict__ seq,   // [B*T, H]
    const float* __restrict__ w,     // [2H]
    const float* __restrict__ bptr,  // [1]
    float* __restrict__ out)         // [B*T]
{
    const int gid  = blockIdx.x * 256 + threadIdx.x;
    const int row  = gid >> 6;
    const int lane = threadIdx.x & 63;
    if (row >= NROWS) return;

    const float* d = dec + (size_t)row * HH;
    const float* s = seq + (size_t)row * HH;

    float acc = 0.f;
    #pragma unroll
    for (int j0 = 0; j0 < HH; j0 += 256) {          // 3 iters, 4 floats/lane
        int j = j0 + lane * 4;
        float4 dv = *reinterpret_cast<const float4*>(d + j);
        float4 wv = *reinterpret_cast<const float4*>(w + j);
        float4 sv = *reinterpret_cast<const float4*>(s + j);
        float4 uv = *reinterpret_cast<const float4*>(w + HH + j);
        acc += dv.x * wv.x + dv.y * wv.y + dv.z * wv.z + dv.w * wv.w;
        acc += sv.x * uv.x + sv.y * uv.y + sv.z * uv.z + sv.w * uv.w;
    }
    #pragma unroll
    for (int off = 32; off > 0; off >>= 1)
        acc += __shfl_down(acc, off, 64);

    if (lane == 0) {
        float x = acc + bptr[0];
        out[row] = 1.f / (1.f + expf(-x));
    }
}

// ---------------------------------------------------------------------------
// Kernel 2: logits[row, v] = sum_{s: ids[b,s]==v} attn[row, s]
// Persistent blocks (4/CU), 4 rows/block, 8 vocab chunks/row, double-buffered
// LDS compose, raw s_barrier + lgkmcnt-only waits (stores never drained in
// the loop). ROUND 5 DELTA: nontemporal stores via native ext_vector_type
// (round 4's HIP float4 rejected by the builtin).
// ---------------------------------------------------------------------------
__global__ __launch_bounds__(512, 8) void scatter_logits(
    const float* __restrict__ attn,  // [B*T, S]
    const int*   __restrict__ ids,   // [B, S]
    float* __restrict__ out_logits)  // [B*T, VOCAB]
{
    __shared__ float smem[2][LDSPAD];
    const int tid  = threadIdx.x;
    const int row0 = blockIdx.x * ROWS_PER_BLK;

    for (int r = 0; r < ROWS_PER_BLK; ++r) {
        const int row = row0 + r;
        const int b   = row >> 9;                       // row / T
        const int v   = ids[b * SS + tid];              // 1 reg/thread
        const float a = attn[(size_t)row * SS + tid];   // 1 reg/thread
        const int shift = (row & 1) ? 2 : 0;
        float* dstrow = out_logits + (size_t)row * VOCAB;

        for (int c = 0; c < NCH; ++c) {
            float* sm = smem[c & 1];
            const int lo = c * NCHUNK;
            const int n  = (c == NCH - 1) ? LASTN : NCHUNK;

            // ---- zero this chunk's buffer ----
            float4* sm4 = reinterpret_cast<float4*>(sm);
            sm4[tid] = make_float4(0.f, 0.f, 0.f, 0.f);
            if (tid < (LDSPAD / 4) - 512)
                sm4[tid + 512] = make_float4(0.f, 0.f, 0.f, 0.f);

            asm volatile("s_waitcnt lgkmcnt(0)" ::: "memory");
            __builtin_amdgcn_s_barrier();

            // ---- scatter: one predicated LDS atomic per thread ----
            int loc = v - lo;
            if ((unsigned)loc < (unsigned)n) atomicAdd(&sm[loc + shift], a);

            asm volatile("s_waitcnt lgkmcnt(0)" ::: "memory");
            __builtin_amdgcn_s_barrier();

            // ---- stream chunk out, NONTEMPORAL; no vmcnt drain after ----
            float* dst = dstrow + lo;
            if (shift && tid == 0) {                    // head 2 floats (odd rows)
                __builtin_nontemporal_store(sm[2], dst);
                __builtin_nontemporal_store(sm[3], dst + 1);
            }
            const int main4 = (n - shift) >> 2;
            const int tail  = n - shift - 4 * main4;    // 0 or 2

            const v4f* s4 = reinterpret_cast<const v4f*>(sm + 2 * shift);
            v4f*       d4 = reinterpret_cast<v4f*>(dst + shift);
            #pragma unroll 2
            for (int i = tid; i < main4; i += 512)
                __builtin_nontemporal_store(s4[i], &d4[i]);

            if (tail && tid == 1) {                     // tail 2 floats
                float* tp = dst + shift + 4 * main4;
                const float* sp = sm + 2 * shift + 4 * main4;
                __builtin_nontemporal_store(sp[0], tp);
                __builtin_nontemporal_store(sp[1], tp + 1);
            }
        }
    }
}

// ---------------------------------------------------------------------------
extern "C" void kernel_launch(void* const* d_in, const int* in_sizes, int n_in,
                              void* d_out, int out_size, void* d_ws, size_t ws_size,
                              hipStream_t stream) {
    const float* dec  = (const float*)d_in[0];   // [B,T,H] f32
    const float* seq  = (const float*)d_in[1];   // [B,T,H] f32
    const float* attn = (const float*)d_in[2];   // [B,T,S] f32
    const int*   ids  = (const int*)  d_in[3];   // [B,S] int32
    const float* w    = (const float*)d_in[4];   // [2H,1] f32
    const float* bp   = (const float*)d_in[5];   // [1] f32

    float* out = (float*)d_out;                  // [B*T] p_gen ++ [B*T,VOCAB] logits

    scatter_logits<<<NBLK, 512, 0, stream>>>(attn, ids, out + NROWS);
    pgen_kernel<<<NROWS / 4, 256, 0, stream>>>(dec, seq, w, bp, out);
}

// Round 6
// 549.371 us; speedup vs baseline: 1.0375x; 1.0375x over previous
//
#include <hip/hip_runtime.h>
#include <math.h>

// Problem constants (from the reference)
#define BB 8
#define TT 512
#define SS 512
#define HH 768
#define VOCAB 32110
#define NROWS (BB * TT)              // 4096
#define NCHUNK 4016                  // floats per vocab chunk
#define NCH 8                        // 7*4016 + 3998 = 32110
#define LASTN (VOCAB - 7 * NCHUNK)   // 3998
#define LDSPAD (NCHUNK + 4)          // 4020 floats = 16080 B per buffer
#define ROWS_PER_BLK 4
#define NBLK (NROWS / ROWS_PER_BLK)  // 1024 = 256 CUs * 4 blocks

// ---------------------------------------------------------------------------
// Fused kernel.
//   Prologue: waves 0..3 each compute p_gen for one of the block's 4 rows
//             (1536-wide dot, float4 loads, shuffle reduce). ~1 µs/block,
//             removes the separate pgen launch.
//   Main:     logits[row, v] = sum_{s: ids[b,s]==v} attn[row, s].
//             Persistent blocks (4/CU), 4 rows/block, 8 vocab chunks/row,
//             double-buffered LDS compose (zero + ds-atomic scatter + read),
//             raw s_barrier + lgkmcnt-only waits — global stores are never
//             drained inside the loop. Plain cached float4 stores (round-5
//             measured nontemporal as a 3.6% regression; reverted).
//             Odd rows (base ≡ 8 mod 16) use the shift-by-2 LDS trick so the
//             main-body stores stay 16B-aligned.
// ---------------------------------------------------------------------------
__global__ __launch_bounds__(512, 8) void fused_copy_mech(
    const float* __restrict__ attn,  // [B*T, S]
    const int*   __restrict__ ids,   // [B, S]
    const float* __restrict__ dec,   // [B*T, H]
    const float* __restrict__ seq,   // [B*T, H]
    const float* __restrict__ w,     // [2H]
    const float* __restrict__ bptr,  // [1]
    float* __restrict__ out_pgen,    // [B*T]
    float* __restrict__ out_logits)  // [B*T, VOCAB]
{
    __shared__ float smem[2][LDSPAD];
    const int tid  = threadIdx.x;
    const int row0 = blockIdx.x * ROWS_PER_BLK;

    // ---- pgen prologue: wave wv -> row row0+wv ----
    {
        const int wv   = tid >> 6;
        const int lane = tid & 63;
        if (wv < ROWS_PER_BLK) {
            const int row = row0 + wv;
            const float* d = dec + (size_t)row * HH;
            const float* s = seq + (size_t)row * HH;
            float acc = 0.f;
            #pragma unroll
            for (int j0 = 0; j0 < HH; j0 += 256) {      // 3 iters, 4 floats/lane
                int j = j0 + lane * 4;
                float4 dv = *reinterpret_cast<const float4*>(d + j);
                float4 wv4 = *reinterpret_cast<const float4*>(w + j);
                float4 sv = *reinterpret_cast<const float4*>(s + j);
                float4 uv = *reinterpret_cast<const float4*>(w + HH + j);
                acc += dv.x * wv4.x + dv.y * wv4.y + dv.z * wv4.z + dv.w * wv4.w;
                acc += sv.x * uv.x + sv.y * uv.y + sv.z * uv.z + sv.w * uv.w;
            }
            #pragma unroll
            for (int off = 32; off > 0; off >>= 1)
                acc += __shfl_down(acc, off, 64);
            if (lane == 0) {
                float x = acc + bptr[0];
                out_pgen[row] = 1.f / (1.f + expf(-x));
            }
        }
    }
    // (no barrier needed: first chunk barrier below synchronizes the block)

    // ---- scatter main loop ----
    for (int r = 0; r < ROWS_PER_BLK; ++r) {
        const int row = row0 + r;
        const int b   = row >> 9;                       // row / T
        const int v   = ids[b * SS + tid];              // 1 reg/thread
        const float a = attn[(size_t)row * SS + tid];   // 1 reg/thread
        const int shift = (row & 1) ? 2 : 0;
        float* dstrow = out_logits + (size_t)row * VOCAB;

        for (int c = 0; c < NCH; ++c) {
            float* sm = smem[c & 1];
            const int lo = c * NCHUNK;
            const int n  = (c == NCH - 1) ? LASTN : NCHUNK;

            // ---- zero this chunk's buffer ----
            float4* sm4 = reinterpret_cast<float4*>(sm);
            sm4[tid] = make_float4(0.f, 0.f, 0.f, 0.f);
            if (tid < (LDSPAD / 4) - 512)
                sm4[tid + 512] = make_float4(0.f, 0.f, 0.f, 0.f);

            asm volatile("s_waitcnt lgkmcnt(0)" ::: "memory");
            __builtin_amdgcn_s_barrier();

            // ---- scatter: one predicated LDS atomic per thread ----
            int loc = v - lo;
            if ((unsigned)loc < (unsigned)n) atomicAdd(&sm[loc + shift], a);

            asm volatile("s_waitcnt lgkmcnt(0)" ::: "memory");
            __builtin_amdgcn_s_barrier();

            // ---- stream chunk out (plain cached float4); no vmcnt drain ----
            float* dst = dstrow + lo;
            if (shift && tid == 0)                      // head float2 (odd rows)
                *reinterpret_cast<float2*>(dst) = make_float2(sm[2], sm[3]);

            const int main4 = (n - shift) >> 2;
            const int tail  = n - shift - 4 * main4;    // 0 or 2

            const float4* s4 = reinterpret_cast<const float4*>(sm + 2 * shift);
            float4*       d4 = reinterpret_cast<float4*>(dst + shift);
            #pragma unroll 2
            for (int i = tid; i < main4; i += 512) d4[i] = s4[i];

            if (tail && tid == 1)                       // tail float2
                *reinterpret_cast<float2*>(dst + shift + 4 * main4) =
                    *reinterpret_cast<const float2*>(sm + 2 * shift + 4 * main4);
        }
    }
}

// ---------------------------------------------------------------------------
extern "C" void kernel_launch(void* const* d_in, const int* in_sizes, int n_in,
                              void* d_out, int out_size, void* d_ws, size_t ws_size,
                              hipStream_t stream) {
    const float* dec  = (const float*)d_in[0];   // [B,T,H] f32
    const float* seq  = (const float*)d_in[1];   // [B,T,H] f32
    const float* attn = (const float*)d_in[2];   // [B,T,S] f32
    const int*   ids  = (const int*)  d_in[3];   // [B,S] int32
    const float* w    = (const float*)d_in[4];   // [2H,1] f32
    const float* bp   = (const float*)d_in[5];   // [1] f32

    float* out = (float*)d_out;                  // [B*T] p_gen ++ [B*T,VOCAB] logits

    fused_copy_mech<<<NBLK, 512, 0, stream>>>(attn, ids, dec, seq, w, bp,
                                              out, out + NROWS);
}